// Round 2
// baseline (334.358 us; speedup 1.0000x reference)
//
#include <hip/hip_runtime.h>
#include <math.h>

#define BATCH   64
#define NTGT    50
#define TOTAL   10647      // 3*(13*13 + 26*26 + 52*52)
#define NC      80
#define ROWLEN  85         // 5 + NUM_CLASSES
#define BT      (BATCH * TOTAL)   // 681408
#define EPSF    1e-7f
#define NBLK    1024       // reduce grid (grid-stride); 1024 blocks = 4/CU

struct Rec { float tx, ty, tw, th, wwh; int cls; };

// ws layout (all offsets bytes):
//   [0)      float acc[8]; int ticket;            (zeroed)
//   [256)    int   slotw[BT]   -- 0 = empty, else record id + 1  (zeroed)
//   [2725888) u32  ignbits[(BT+31)/32]            (zeroed)
//   [2811136) Rec  rec[BATCH*NTGT]                (no init needed)
#define OFF_SLOT  256
#define OFF_IGN   (OFF_SLOT + BT * 4)                    // 2,725,888
#define CLR_BYTES (OFF_IGN + ((BT + 31) / 32) * 4 + 60)  // ~2.81 MB, pad
#define OFF_REC   2811136

// ---------------------------------------------------------------------------
// Kernel 1: build targets. One thread per (b, n) ground-truth box.
// ---------------------------------------------------------------------------
__global__ __launch_bounds__(256) void build_targets_k(
    const float* __restrict__ tgt,
    int* __restrict__ slotw,
    unsigned int* __restrict__ ignbits,
    Rec* __restrict__ rec)
{
    int i = blockIdx.x * blockDim.x + threadIdx.x;
    if (i >= BATCH * NTGT) return;

    const float* t = tgt + (size_t)i * 5;
    float c = t[0], x = t[1], y = t[2], w = t[3], h = t[4];
    if (c + x + y + w + h == 0.0f) return;   // valid = sum(targets,-1) != 0

    int b = i / NTGT;

    const float FM[3]  = {13.f, 26.f, 52.f};
    const int   OFF[3] = {0, 507, 2535};     // 0, 3*13*13, +3*26*26
    const float AW[3][3] = {{3.625f, 4.875f, 11.65625f},
                            {1.875f, 3.875f, 3.6875f},
                            {1.25f,  2.0f,   4.125f}};
    const float AH[3][3] = {{2.8125f, 6.1875f, 10.1875f},
                            {3.8125f, 2.8125f, 7.4375f},
                            {1.625f,  3.75f,   2.875f}};

    float best_all = -1.0f;
    int   best_idx = 0;
    for (int m = 0; m < 3; ++m) {
        float fm = FM[m];
        float gw = w * fm, gh = h * fm;
        int gi = (int)(x * fm);
        int gj = (int)(y * fm);
        int base = OFF[m] + 3 * gi * gj;     // reference uses A*gi*gj (product)
        float bl = -1.0f; int ba = 0;
        for (int a = 0; a < 3; ++a) {
            float inter = fminf(gw, AW[m][a]) * fminf(gh, AH[m][a]);
            float uni   = gw * gh + AW[m][a] * AH[m][a] - inter;
            float iou   = inter / (uni + 1e-16f);
            if (iou > 0.5f) {
                int pos = b * TOTAL + base + a;
                atomicOr(&ignbits[pos >> 5], 1u << (pos & 31));
            }
            if (iou > bl) { bl = iou; ba = a; }          // first-max tie-break
        }
        if (bl > best_all) { best_all = bl; best_idx = base + ba; }
    }

    Rec r;
    r.tx = x * 416.0f; r.ty = y * 416.0f;
    r.tw = w * 416.0f; r.th = h * 416.0f;
    r.wwh = 2.0f - w * h;
    r.cls = (int)c;
    rec[i] = r;

    // last-write-wins across duplicate cells: record id monotone in n
    atomicMax(&slotw[b * TOTAL + best_idx], i + 1);
}

// ---------------------------------------------------------------------------
// Kernel 2: fused loss reduction + finalize (last-block ticket).
// acc = {sum_x, sum_y, sum_w, sum_h, sum_obj_winner, sum_noobj, sum_cls, cnt}
// ---------------------------------------------------------------------------
__global__ __launch_bounds__(256) void reduce_loss_k(
    const float* __restrict__ pred,
    const int* __restrict__ slotw,
    const unsigned int* __restrict__ ignbits,
    const Rec* __restrict__ rec,
    float* __restrict__ acc,
    int* __restrict__ ticket,
    float* __restrict__ out)
{
    const float NEG_LOG_1ME = 1.00000011921e-07f;   // -log(1-1e-7) in f32

    float sx = 0.f, sy = 0.f, sw = 0.f, sh = 0.f;
    float sb1 = 0.f, sb2 = 0.f, scl = 0.f, cnt = 0.f;

    for (int i = blockIdx.x * blockDim.x + threadIdx.x; i < BT;
         i += NBLK * 256) {
        const float* row = pred + (size_t)i * ROWLEN;
        float conf = row[4];
        float cc = fminf(fmaxf(conf, EPSF), 1.0f - EPSF);

        // 0.5-weighted noobj bce: p = clip(conf*noobj), t = 0
        bool ig = (ignbits[i >> 5] >> (i & 31)) & 1u;
        sb2 += ig ? NEG_LOG_1ME : -__logf(1.0f - cc);

        int s = slotw[i];
        if (s > 0) {
            Rec r = rec[s - 1];
            float dx = (row[0] - r.tx) * r.wwh;
            float dy = (row[1] - r.ty) * r.wwh;
            float dw = (row[2] - r.tw) * r.wwh;
            float dh = (row[3] - r.th) * r.wwh;
            sx += dx * dx; sy += dy * dy; sw += dw * dw; sh += dh * dh;
            sb1 += -__logf(cc);       // p = clip(conf), t = 1
            cnt += 1.0f;
            int cid = r.cls;
            #pragma unroll 4
            for (int k = 0; k < NC; ++k) {
                float p = row[5 + k];
                p = fminf(fmaxf(p, EPSF), 1.0f - EPSF);
                scl += (k == cid) ? -__logf(p) : -__logf(1.0f - p);
            }
        }
        // non-winner obj term (p=eps, t=0) is the constant NEG_LOG_1ME,
        // folded analytically into the finalize below.
    }

    // block reduction: wave shuffle then cross-wave via LDS
    __shared__ float red[4][8];
    float v[8] = {sx, sy, sw, sh, sb1, sb2, scl, cnt};
    int lane = threadIdx.x & 63, wid = threadIdx.x >> 6;
    #pragma unroll
    for (int k = 0; k < 8; ++k) {
        float t = v[k];
        #pragma unroll
        for (int o = 32; o > 0; o >>= 1) t += __shfl_down(t, o, 64);
        if (lane == 0) red[wid][k] = t;
    }
    __syncthreads();
    if (wid == 0 && lane < 8) {
        float t = red[0][lane] + red[1][lane] + red[2][lane] + red[3][lane];
        atomicAdd(&acc[lane], t);
    }
    __syncthreads();

    if (threadIdx.x == 0) {
        __threadfence();
        int old = atomicAdd(ticket, 1);
        if (old == NBLK - 1) {          // last block: finalize
            float a[8];
            #pragma unroll
            for (int k = 0; k < 8; ++k) a[k] = atomicAdd(&acc[k], 0.0f);
            float inv  = 1.0f / (float)BT;
            float nsel = fmaxf(a[7], 1.0f);
            float obj  = a[4] + ((float)BT - a[7]) * NEG_LOG_1ME;
            float loss = (a[0] + a[1] + a[2] + a[3] + obj + 0.5f * a[5]) * inv
                       + a[6] / (nsel * (float)NC);
            out[0] = loss;
        }
    }
}

// ---------------------------------------------------------------------------
extern "C" void kernel_launch(void* const* d_in, const int* in_sizes, int n_in,
                              void* d_out, int out_size, void* d_ws, size_t ws_size,
                              hipStream_t stream)
{
    const float* pred = (const float*)d_in[0];   // (64, 10647, 85) f32
    const float* tgt  = (const float*)d_in[1];   // (64, 50, 5)     f32
    float* out = (float*)d_out;

    char* ws = (char*)d_ws;
    float*        acc     = (float*)ws;
    int*          ticket  = (int*)(ws + 32);
    int*          slotw   = (int*)(ws + OFF_SLOT);
    unsigned int* ignbits = (unsigned int*)(ws + OFF_IGN);
    Rec*          rec     = (Rec*)(ws + OFF_REC);

    hipMemsetAsync(ws, 0, CLR_BYTES, stream);    // acc+ticket+slotw+ignbits

    build_targets_k<<<(BATCH * NTGT + 255) / 256, 256, 0, stream>>>(
        tgt, slotw, ignbits, rec);
    reduce_loss_k<<<NBLK, 256, 0, stream>>>(
        pred, slotw, ignbits, rec, acc, ticket, out);
}

// Round 3
// 304.104 us; speedup vs baseline: 1.0995x; 1.0995x over previous
//
#include <hip/hip_runtime.h>
#include <math.h>

#define BATCH   64
#define NTGT    50
#define TOTAL   10647      // 3*(13*13 + 26*26 + 52*52)
#define NC      80
#define ROWLEN  85         // 5 + NUM_CLASSES
#define BT      (BATCH * TOTAL)   // 681408
#define EPSF    1e-7f

struct Rec { float tx, ty, tw, th, wwh; int cls; };

// ws layout (bytes):
//   [0)        float acc[8]                       (zeroed)
//   [256)      int   slotw[BT]  0=empty else id+1 (zeroed)
//   [2725888)  u32   ignbits[(BT+31)/32]          (zeroed)
//   [2811136)  Rec   rec[BATCH*NTGT]              (no init needed)
#define OFF_SLOT  256
#define OFF_IGN   (OFF_SLOT + BT * 4)              // 2,725,888
#define CLR_BYTES 2811136                          // covers acc+slot+ignbits
#define OFF_REC   2811136

// ---------------------------------------------------------------------------
// Kernel 1: build targets. One thread per (b, n) ground-truth box.
// ---------------------------------------------------------------------------
__global__ __launch_bounds__(256) void build_targets_k(
    const float* __restrict__ tgt,
    int* __restrict__ slotw,
    unsigned int* __restrict__ ignbits,
    Rec* __restrict__ rec)
{
    int i = blockIdx.x * blockDim.x + threadIdx.x;
    if (i >= BATCH * NTGT) return;

    const float* t = tgt + (size_t)i * 5;
    float c = t[0], x = t[1], y = t[2], w = t[3], h = t[4];
    if (c + x + y + w + h == 0.0f) return;   // valid = sum(targets,-1) != 0

    int b = i / NTGT;

    const float FM[3]  = {13.f, 26.f, 52.f};
    const int   OFF[3] = {0, 507, 2535};     // 0, 3*13*13, +3*26*26
    const float AW[3][3] = {{3.625f, 4.875f, 11.65625f},
                            {1.875f, 3.875f, 3.6875f},
                            {1.25f,  2.0f,   4.125f}};
    const float AH[3][3] = {{2.8125f, 6.1875f, 10.1875f},
                            {3.8125f, 2.8125f, 7.4375f},
                            {1.625f,  3.75f,   2.875f}};

    float best_all = -1.0f;
    int   best_idx = 0;
    for (int m = 0; m < 3; ++m) {
        float fm = FM[m];
        float gw = w * fm, gh = h * fm;
        int gi = (int)(x * fm);
        int gj = (int)(y * fm);
        int base = OFF[m] + 3 * gi * gj;     // reference uses A*gi*gj (product)
        float bl = -1.0f; int ba = 0;
        for (int a = 0; a < 3; ++a) {
            float inter = fminf(gw, AW[m][a]) * fminf(gh, AH[m][a]);
            float uni   = gw * gh + AW[m][a] * AH[m][a] - inter;
            float iou   = inter / (uni + 1e-16f);
            if (iou > 0.5f) {
                int pos = b * TOTAL + base + a;
                atomicOr(&ignbits[pos >> 5], 1u << (pos & 31));
            }
            if (iou > bl) { bl = iou; ba = a; }          // first-max tie-break
        }
        if (bl > best_all) { best_all = bl; best_idx = base + ba; }
    }

    Rec r;
    r.tx = x * 416.0f; r.ty = y * 416.0f;
    r.tw = w * 416.0f; r.th = h * 416.0f;
    r.wwh = 2.0f - w * h;
    r.cls = (int)c;
    rec[i] = r;

    // last-write-wins across duplicate cells: record id monotone in n
    atomicMax(&slotw[b * TOTAL + best_idx], i + 1);
}

// ---------------------------------------------------------------------------
// Kernel 2: fused loss reduction, one thread per position (flat grid).
// acc = {sum_x, sum_y, sum_w, sum_h, sum_obj_winner, sum_noobj, sum_cls, cnt}
// ---------------------------------------------------------------------------
__global__ __launch_bounds__(256) void reduce_loss_k(
    const float* __restrict__ pred,
    const int* __restrict__ slotw,
    const unsigned int* __restrict__ ignbits,
    const Rec* __restrict__ rec,
    float* __restrict__ acc)
{
    const float NEG_LOG_1ME = 1.00000011921e-07f;   // -log(1-1e-7) in f32

    float sx = 0.f, sy = 0.f, sw = 0.f, sh = 0.f;
    float sb1 = 0.f, sb2 = 0.f, scl = 0.f, cnt = 0.f;

    int i = blockIdx.x * blockDim.x + threadIdx.x;
    if (i < BT) {
        const float* row = pred + (size_t)i * ROWLEN;
        float conf = row[4];
        float cc = fminf(fmaxf(conf, EPSF), 1.0f - EPSF);

        // 0.5-weighted noobj bce: p = clip(conf*noobj), t = 0
        bool ig = (ignbits[i >> 5] >> (i & 31)) & 1u;
        sb2 = ig ? NEG_LOG_1ME : -__logf(1.0f - cc);

        int s = slotw[i];
        if (s > 0) {
            Rec r = rec[s - 1];
            float dx = (row[0] - r.tx) * r.wwh;
            float dy = (row[1] - r.ty) * r.wwh;
            float dw = (row[2] - r.tw) * r.wwh;
            float dh = (row[3] - r.th) * r.wwh;
            sx = dx * dx; sy = dy * dy; sw = dw * dw; sh = dh * dh;
            sb1 = -__logf(cc);        // p = clip(conf), t = 1
            cnt = 1.0f;
            int cid = r.cls;
            #pragma unroll 4
            for (int k = 0; k < NC; ++k) {
                float p = row[5 + k];
                p = fminf(fmaxf(p, EPSF), 1.0f - EPSF);
                scl += (k == cid) ? -__logf(p) : -__logf(1.0f - p);
            }
        }
        // non-winner obj term (p=eps, t=0) is constant; folded in finalize.
    }

    // block reduction: wave shuffle then cross-wave via LDS
    __shared__ float red[4][8];
    float v[8] = {sx, sy, sw, sh, sb1, sb2, scl, cnt};
    int lane = threadIdx.x & 63, wid = threadIdx.x >> 6;
    #pragma unroll
    for (int k = 0; k < 8; ++k) {
        float t = v[k];
        #pragma unroll
        for (int o = 32; o > 0; o >>= 1) t += __shfl_down(t, o, 64);
        if (lane == 0) red[wid][k] = t;
    }
    __syncthreads();
    if (wid == 0 && lane < 8) {
        float t = red[0][lane] + red[1][lane] + red[2][lane] + red[3][lane];
        atomicAdd(&acc[lane], t);
    }
}

__global__ void finalize_k(const float* __restrict__ acc, float* __restrict__ out)
{
    const float NEG_LOG_1ME = 1.00000011921e-07f;
    float inv  = 1.0f / (float)BT;
    float nsel = fmaxf(acc[7], 1.0f);
    float obj  = acc[4] + ((float)BT - acc[7]) * NEG_LOG_1ME;
    float loss = (acc[0] + acc[1] + acc[2] + acc[3] + obj + 0.5f * acc[5]) * inv
               + acc[6] / (nsel * (float)NC);
    out[0] = loss;
}

// ---------------------------------------------------------------------------
extern "C" void kernel_launch(void* const* d_in, const int* in_sizes, int n_in,
                              void* d_out, int out_size, void* d_ws, size_t ws_size,
                              hipStream_t stream)
{
    const float* pred = (const float*)d_in[0];   // (64, 10647, 85) f32
    const float* tgt  = (const float*)d_in[1];   // (64, 50, 5)     f32
    float* out = (float*)d_out;

    char* ws = (char*)d_ws;
    float*        acc     = (float*)ws;
    int*          slotw   = (int*)(ws + OFF_SLOT);
    unsigned int* ignbits = (unsigned int*)(ws + OFF_IGN);
    Rec*          rec     = (Rec*)(ws + OFF_REC);

    hipMemsetAsync(ws, 0, CLR_BYTES, stream);    // acc + slotw + ignbits

    build_targets_k<<<(BATCH * NTGT + 255) / 256, 256, 0, stream>>>(
        tgt, slotw, ignbits, rec);
    reduce_loss_k<<<(BT + 255) / 256, 256, 0, stream>>>(
        pred, slotw, ignbits, rec, acc);
    finalize_k<<<1, 1, 0, stream>>>(acc, out);
}

// Round 4
// 294.049 us; speedup vs baseline: 1.1371x; 1.0342x over previous
//
#include <hip/hip_runtime.h>
#include <math.h>

#define BATCH   64
#define NTGT    50
#define TOTAL   10647      // 3*(13*13 + 26*26 + 52*52)
#define NC      80
#define ROWLEN  85         // 5 + NUM_CLASSES
#define EPSF    1e-7f
#define BPB     42         // blocks per batch: ceil(10647/256)
#define NBLKS   (BATCH * BPB)     // 2688
#define NEG_LOG_1ME 1.00000011921e-07f   // -log(1-1e-7) in f32

// ws layout: float partials[NBLKS][8] at offset 0 (86,016 B, no init needed:
// every block unconditionally stores all 8 of its partial sums).

// ---------------------------------------------------------------------------
// Fused kernel: each block owns a 256-position window of one batch image.
// It redundantly recomputes that batch's 50 targets (threads 0..49, ~40 FLOP
// each), builds the slot/ignore map for its window in LDS, then does the
// per-position loss math and a block reduction into partials[block][8].
// ---------------------------------------------------------------------------
__global__ __launch_bounds__(256) void fused_loss_k(
    const float* __restrict__ pred,
    const float* __restrict__ tgt,
    float* __restrict__ partials)
{
    __shared__ int           slot_lds[256];   // 0 = empty, else target n + 1
    __shared__ unsigned char ign_lds[256];
    __shared__ float r_tx[NTGT], r_ty[NTGT], r_tw[NTGT], r_th[NTGT], r_wwh[NTGT];
    __shared__ int   r_cls[NTGT];
    __shared__ float red[4][8];

    const int b   = blockIdx.x / BPB;
    const int lo  = (blockIdx.x % BPB) * 256;
    const int tid = threadIdx.x;

    slot_lds[tid] = 0;
    ign_lds[tid]  = 0;
    __syncthreads();

    if (tid < NTGT) {
        const float* t = tgt + ((size_t)b * NTGT + tid) * 5;
        float c = t[0], x = t[1], y = t[2], w = t[3], h = t[4];
        if (c + x + y + w + h != 0.0f) {       // valid = sum(targets,-1) != 0
            const float FM[3]  = {13.f, 26.f, 52.f};
            const int   OFF[3] = {0, 507, 2535};
            const float AW[3][3] = {{3.625f, 4.875f, 11.65625f},
                                    {1.875f, 3.875f, 3.6875f},
                                    {1.25f,  2.0f,   4.125f}};
            const float AH[3][3] = {{2.8125f, 6.1875f, 10.1875f},
                                    {3.8125f, 2.8125f, 7.4375f},
                                    {1.625f,  3.75f,   2.875f}};
            float best_all = -1.0f;
            int   best_idx = 0;
            for (int m = 0; m < 3; ++m) {
                float fm = FM[m];
                float gw = w * fm, gh = h * fm;
                int gi = (int)(x * fm);
                int gj = (int)(y * fm);
                int base = OFF[m] + 3 * gi * gj;   // reference: A*gi*gj (product)
                float bl = -1.0f; int ba = 0;
                for (int a = 0; a < 3; ++a) {
                    float inter = fminf(gw, AW[m][a]) * fminf(gh, AH[m][a]);
                    float uni   = gw * gh + AW[m][a] * AH[m][a] - inter;
                    float iou   = inter / (uni + 1e-16f);
                    if (iou > 0.5f) {
                        int p = base + a - lo;     // ignore scatter, this window?
                        if ((unsigned)p < 256u) ign_lds[p] = 1;
                    }
                    if (iou > bl) { bl = iou; ba = a; }   // first-max tie-break
                }
                if (bl > best_all) { best_all = bl; best_idx = base + ba; }
            }
            r_tx[tid]  = x * 416.0f;  r_ty[tid] = y * 416.0f;
            r_tw[tid]  = w * 416.0f;  r_th[tid] = h * 416.0f;
            r_wwh[tid] = 2.0f - w * h;
            r_cls[tid] = (int)c;
            int p = best_idx - lo;
            // last-write-wins across duplicate cells: id monotone in n
            if ((unsigned)p < 256u) atomicMax(&slot_lds[p], tid + 1);
        }
    }
    __syncthreads();

    // acc = {sum_x, sum_y, sum_w, sum_h, sum_obj_winner, sum_noobj, sum_cls, cnt}
    float sx = 0.f, sy = 0.f, sw = 0.f, sh = 0.f;
    float sb1 = 0.f, sb2 = 0.f, scl = 0.f, cnt = 0.f;

    int pos = lo + tid;
    if (pos < TOTAL) {
        const float* row = pred + ((size_t)b * TOTAL + pos) * ROWLEN;
        float conf = row[4];
        float cc = fminf(fmaxf(conf, EPSF), 1.0f - EPSF);

        // 0.5-weighted noobj bce: p = clip(conf*noobj), t = 0
        sb2 = ign_lds[tid] ? NEG_LOG_1ME : -__logf(1.0f - cc);

        int s = slot_lds[tid];
        if (s > 0) {
            int n = s - 1;
            float wwh = r_wwh[n];
            float dx = (row[0] - r_tx[n]) * wwh;
            float dy = (row[1] - r_ty[n]) * wwh;
            float dw = (row[2] - r_tw[n]) * wwh;
            float dh = (row[3] - r_th[n]) * wwh;
            sx = dx * dx; sy = dy * dy; sw = dw * dw; sh = dh * dh;
            sb1 = -__logf(cc);        // p = clip(conf), t = 1
            cnt = 1.0f;
            int cid = r_cls[n];
            #pragma unroll 4
            for (int k = 0; k < NC; ++k) {
                float p = row[5 + k];
                p = fminf(fmaxf(p, EPSF), 1.0f - EPSF);
                scl += (k == cid) ? -__logf(p) : -__logf(1.0f - p);
            }
        }
        // non-winner obj term (p=eps, t=0) is constant; folded in finalize.
    }

    // block reduction: wave shuffle, then cross-wave via LDS
    float v[8] = {sx, sy, sw, sh, sb1, sb2, scl, cnt};
    int lane = tid & 63, wid = tid >> 6;
    #pragma unroll
    for (int k = 0; k < 8; ++k) {
        float t = v[k];
        #pragma unroll
        for (int o = 32; o > 0; o >>= 1) t += __shfl_down(t, o, 64);
        if (lane == 0) red[wid][k] = t;
    }
    __syncthreads();
    if (wid == 0 && lane < 8)
        partials[(size_t)blockIdx.x * 8 + lane] =
            red[0][lane] + red[1][lane] + red[2][lane] + red[3][lane];
}

// ---------------------------------------------------------------------------
// Finalize: reduce NBLKS x 8 partials, emit scalar loss.
// ---------------------------------------------------------------------------
__global__ __launch_bounds__(256) void finalize_k(
    const float* __restrict__ partials, float* __restrict__ out)
{
    __shared__ float red[4][8];
    float v[8] = {0.f, 0.f, 0.f, 0.f, 0.f, 0.f, 0.f, 0.f};
    for (int r = threadIdx.x; r < NBLKS; r += 256) {
        #pragma unroll
        for (int k = 0; k < 8; ++k) v[k] += partials[(size_t)r * 8 + k];
    }
    int lane = threadIdx.x & 63, wid = threadIdx.x >> 6;
    #pragma unroll
    for (int k = 0; k < 8; ++k) {
        float t = v[k];
        #pragma unroll
        for (int o = 32; o > 0; o >>= 1) t += __shfl_down(t, o, 64);
        if (lane == 0) red[wid][k] = t;
    }
    __syncthreads();
    if (threadIdx.x == 0) {
        float a[8];
        #pragma unroll
        for (int k = 0; k < 8; ++k)
            a[k] = red[0][k] + red[1][k] + red[2][k] + red[3][k];
        const float BT = (float)(BATCH * TOTAL);
        float inv  = 1.0f / BT;
        float nsel = fmaxf(a[7], 1.0f);
        float obj  = a[4] + (BT - a[7]) * NEG_LOG_1ME;  // non-winner obj bce
        out[0] = (a[0] + a[1] + a[2] + a[3] + obj + 0.5f * a[5]) * inv
               + a[6] / (nsel * (float)NC);
    }
}

// ---------------------------------------------------------------------------
extern "C" void kernel_launch(void* const* d_in, const int* in_sizes, int n_in,
                              void* d_out, int out_size, void* d_ws, size_t ws_size,
                              hipStream_t stream)
{
    const float* pred = (const float*)d_in[0];   // (64, 10647, 85) f32
    const float* tgt  = (const float*)d_in[1];   // (64, 50, 5)     f32
    float* out = (float*)d_out;
    float* partials = (float*)d_ws;              // [NBLKS][8], no init needed

    fused_loss_k<<<NBLKS, 256, 0, stream>>>(pred, tgt, partials);
    finalize_k<<<1, 256, 0, stream>>>(partials, out);
}